// Round 19
// baseline (18.500 us; speedup 1.0000x reference)
//
#include <hip/hip_runtime.h>

#define NQ 12

typedef _Float16 hf2 __attribute__((ext_vector_type(2)));

struct C2 { float r, i; };
__device__ __forceinline__ C2 cmul(C2 a, C2 b){ return C2{a.r*b.r - a.i*b.i, a.r*b.i + a.i*b.r}; }
__device__ __forceinline__ C2 cadd(C2 a, C2 b){ return C2{a.r + b.r, a.i + b.i}; }

__device__ __forceinline__ unsigned pk_rep(float v){
    union { _Float16 h[2]; unsigned u; } c;
    c.h[0] = (_Float16)v; c.h[1] = (_Float16)v;
    return c.u;
}
__device__ __forceinline__ hf2 u2h(unsigned u){
    union { unsigned u; hf2 h; } c; c.u = u; return c.h;
}
__device__ __forceinline__ float rlane_f(float v, int l){
    union { float f; int i; } c; c.f = v;
    c.i = __builtin_amdgcn_readlane(c.i, l);
    return c.f;
}
__device__ __forceinline__ unsigned rlane_u(unsigned v, int l){
    return (unsigned)__builtin_amdgcn_readlane((int)v, l);
}
// flip sign of v where m has bit31 set (m = 0 or 0x80000000)
__device__ __forceinline__ float xsign(float v, int m){
    union { float f; int i; } c; c.f = v;
    c.i ^= m;
    return c.f;
}

// DPP move with old=0 (all our patterns read only valid lanes, old unused).
template<int CTRL>
__device__ __forceinline__ float dppmv(float x){
    union { float f; int i; } c; c.f = x;
    c.i = __builtin_amdgcn_update_dpp(0, c.i, CTRL, 0xf, 0xf, false);
    return c.f;
}
// rocPRIM wave64 sum: 4x row_shr prefix + row_bcast15 + row_bcast31.
// Total lands in lane 63. Pure VALU — zero DS-pipe traffic.
__device__ __forceinline__ float wsum63(float x){
    x += dppmv<0x111>(x);   // row_shr:1
    x += dppmv<0x112>(x);   // row_shr:2
    x += dppmv<0x114>(x);   // row_shr:4
    x += dppmv<0x118>(x);   // row_shr:8
    x += dppmv<0x142>(x);   // row_bcast:15
    x += dppmv<0x143>(x);   // row_bcast:31
    return x;
}

// xor-exchange of a 32-bit value: DPP (1-cyc VALU) for masks 1,2,8;
// ds_bpermute (__shfl_xor) otherwise.
//   xor1 = quad_perm[1,0,3,2] (0xB1), xor2 = quad_perm[2,3,0,1] (0x4E),
//   xor8 = row_ror:8 (0x128): within a 16-row, (l+8)%16 == l^8.
template<int XM>
__device__ __forceinline__ hf2 xswap(hf2 v){
    union { hf2 h; int i; } c; c.h = v;
    if constexpr (XM == 1)      c.i = __builtin_amdgcn_update_dpp(0, c.i, 0xB1,  0xF, 0xF, false);
    else if constexpr (XM == 2) c.i = __builtin_amdgcn_update_dpp(0, c.i, 0x4E,  0xF, 0xF, false);
    else if constexpr (XM == 8) c.i = __builtin_amdgcn_update_dpp(0, c.i, 0x128, 0xF, 0xF, false);
    else                        c.i = __shfl_xor(c.i, XM);
    return c.h;
}

// One f16-packed gate stage: 2 exchanges + 8 v_pk_fma_f16.
template<int XM>
__device__ __forceinline__ void gate_pkT(hf2& Ur, hf2& Ui,
                                         hf2 gar, hf2 gai, hf2 gbr, hf2 gbi){
    hf2 Or = xswap<XM>(Ur);
    hf2 Oi = xswap<XM>(Ui);
    hf2 nr = gar*Ur - gai*Ui + gbr*Or - gbi*Oi;
    hf2 ni = gar*Ui + gai*Ur + gbr*Oi + gbi*Or;
    Ur = nr; Ui = ni;
}

// One cascade stage: fetch gate constants from lane L, apply on bit SH.
template<int SH>
__device__ __forceinline__ void stage(int L, int lane,
        unsigned pk0, unsigned pk1, unsigned pk2, unsigned pk3,
        unsigned pk4, unsigned pk5, unsigned pk6, unsigned pk7,
        hf2& Ur, hf2& Ui){
    unsigned c0 = rlane_u(pk0, L), c1 = rlane_u(pk1, L);
    unsigned c2 = rlane_u(pk2, L), c3 = rlane_u(pk3, L);
    unsigned c4 = rlane_u(pk4, L), c5 = rlane_u(pk5, L);
    unsigned c6 = rlane_u(pk6, L), c7 = rlane_u(pk7, L);
    const int bit = (lane >> SH) & 1;
    hf2 gar = u2h(bit ? c6 : c0);
    hf2 gai = u2h(bit ? c7 : c1);
    hf2 gbr = u2h(bit ? c4 : c2);
    hf2 gbi = u2h(bit ? c5 : c3);
    gate_pkT<(1 << SH)>(Ur, Ui, gar, gai, gbr, gbi);
}

// SINGLE-KERNEL rank-2 evaluation, one element per wave. Gates computed
// in-wave (one per lane); cascades in packed f16 with DPP exchanges where
// the xor mask allows (1,2,8); epilogue reductions pure-VALU DPP.
__global__ __launch_bounds__(256, 5)
void qsim(const float* __restrict__ x, const float* __restrict__ wts,
          float* __restrict__ out, int B){
    const int tid  = threadIdx.x;
    const int lane = tid & 63;
    const int wid  = tid >> 6;
    int b = blockIdx.x * 4 + wid;
    if (b >= B) return;
    b = __builtin_amdgcn_readfirstlane(b);

    // ---- per-lane fused gate t = lane (lanes 0..23; others duplicate t=0) ----
    const int t = (lane < 24) ? lane : 0;
    float wa = wts[3*t], wb = wts[3*t+1], wc = wts[3*t+2];
    float sa, ca, sb, cb, sc, cc;
    __sincosf(0.5f*wa, &sa, &ca);
    __sincosf(0.5f*wb, &sb, &cb);
    __sincosf(0.5f*wc, &sc, &cc);
    float gf0, gf1, gf2, gf3, gf4, gf5, gf6, gf7;
    {
        C2 rx00{ca,0.f}, rx01{0.f,-sa}, rx10{0.f,-sa}, rx11{ca,0.f};
        C2 ry00{cb,0.f}, ry01{-sb,0.f}, ry10{sb,0.f}, ry11{cb,0.f};
        C2 m00 = cadd(cmul(ry00,rx00), cmul(ry01,rx10));
        C2 m01 = cadd(cmul(ry00,rx01), cmul(ry01,rx11));
        C2 m10 = cadd(cmul(ry10,rx00), cmul(ry11,rx10));
        C2 m11 = cadd(cmul(ry10,rx01), cmul(ry11,rx11));
        C2 e0{cc,-sc}, e1{cc,sc};
        C2 g00 = cmul(e0,m00), g01 = cmul(e0,m01);
        C2 g10 = cmul(e1,m10), g11 = cmul(e1,m11);
        gf0 = g00.r; gf1 = g00.i; gf2 = g01.r; gf3 = g01.i;
        gf4 = g10.r; gf5 = g10.i; gf6 = g11.r; gf7 = g11.i;
    }
    // replicated-f16 packed words (meaningful on lanes 12..23)
    unsigned pk0 = pk_rep(gf0), pk1 = pk_rep(gf1), pk2 = pk_rep(gf2), pk3 = pk_rep(gf3);
    unsigned pk4 = pk_rep(gf4), pk5 = pk_rep(gf5), pk6 = pk_rep(gf6), pk7 = pk_rep(gf7);

    // ---- layer-0 prep: lane w (w<12) computes v_w from its OWN gate ----
    const int wl = (lane < 12) ? lane : 0;
    float xw = x[(size_t)b * NQ + wl];
    float sx, cx;
    __sincosf(0.5f * xw, &sx, &cx);
    float r0v = gf0*cx + gf2*sx;
    float i0v = gf1*cx + gf3*sx;
    float r1v = gf4*cx + gf6*sx;
    float i1v = gf5*cx + gf7*sx;

    // redistribute: V[lane] = component (lane&3) of wire (lane>>2)
    const int srcw = lane >> 2;
    float B0 = __shfl(r0v, srcw);
    float B1 = __shfl(i0v, srcw);
    float B2 = __shfl(r1v, srcw);
    float B3 = __shfl(i1v, srcw);
    const int comp = lane & 3;
    float V = (comp == 0) ? B0 : (comp == 1) ? B1 : (comp == 2) ? B2 : B3;

    // v6 (uniform) for the w_p combine
    float v6r0 = rlane_f(V, 24), v6i0 = rlane_f(V, 25);
    float v6r1 = rlane_f(V, 26), v6i1 = rlane_f(V, 27);

    // ---- H2[j], j = lane: gray product over wires 0..5 ----
    float h2r, h2i;
    {
        const int g0b = (lane>>5)&1;
        const int g1b = ((lane>>4)^(lane>>5))&1;
        const int g2b = ((lane>>3)^(lane>>4))&1;
        const int g3b = ((lane>>2)^(lane>>3))&1;
        const int g4b = ((lane>>1)^(lane>>2))&1;
        const int g5b = ( lane    ^(lane>>1))&1;
        int s0 = 2*g0b;
        h2r = __shfl(V, s0); h2i = __shfl(V, s0+1);
        {   int s = 4*1 + 2*g1b; float ar=__shfl(V,s), ai=__shfl(V,s+1);
            float nr=h2r*ar-h2i*ai, ni=h2r*ai+h2i*ar; h2r=nr; h2i=ni; }
        {   int s = 4*2 + 2*g2b; float ar=__shfl(V,s), ai=__shfl(V,s+1);
            float nr=h2r*ar-h2i*ai, ni=h2r*ai+h2i*ar; h2r=nr; h2i=ni; }
        {   int s = 4*3 + 2*g3b; float ar=__shfl(V,s), ai=__shfl(V,s+1);
            float nr=h2r*ar-h2i*ai, ni=h2r*ai+h2i*ar; h2r=nr; h2i=ni; }
        {   int s = 4*4 + 2*g4b; float ar=__shfl(V,s), ai=__shfl(V,s+1);
            float nr=h2r*ar-h2i*ai, ni=h2r*ai+h2i*ar; h2r=nr; h2i=ni; }
        {   int s = 4*5 + 2*g5b; float ar=__shfl(V,s), ai=__shfl(V,s+1);
            float nr=h2r*ar-h2i*ai, ni=h2r*ai+h2i*ar; h2r=nr; h2i=ni; }
    }
    // ---- base[l], l = lane: gray product over wires 7..11 ----
    float bsr, bsi;
    {
        const int b1 = ((lane>>4)^(lane>>5))&1;
        const int b2 = ((lane>>3)^(lane>>4))&1;
        const int b3 = ((lane>>2)^(lane>>3))&1;
        const int b4 = ((lane>>1)^(lane>>2))&1;
        const int b5 = ( lane    ^(lane>>1))&1;
        int s0 = 4*7 + 2*b1;
        bsr = __shfl(V, s0); bsi = __shfl(V, s0+1);
        {   int s = 4*8 + 2*b2;  float ar=__shfl(V,s), ai=__shfl(V,s+1);
            float nr=bsr*ar-bsi*ai, ni=bsr*ai+bsi*ar; bsr=nr; bsi=ni; }
        {   int s = 4*9 + 2*b3;  float ar=__shfl(V,s), ai=__shfl(V,s+1);
            float nr=bsr*ar-bsi*ai, ni=bsr*ai+bsi*ar; bsr=nr; bsi=ni; }
        {   int s = 4*10 + 2*b4; float ar=__shfl(V,s), ai=__shfl(V,s+1);
            float nr=bsr*ar-bsi*ai, ni=bsr*ai+bsi*ar; bsr=nr; bsi=ni; }
        {   int s = 4*11 + 2*b5; float ar=__shfl(V,s), ai=__shfl(V,s+1);
            float nr=bsr*ar-bsi*ai, ni=bsr*ai+bsi*ar; bsr=nr; bsi=ni; }
    }

    // ---- masked starting vector-pairs, packed f16 componentwise ----
    const int jpar = lane & 1;
    const int l5   = (lane >> 5) & 1;
    const _Float16 HZ = (_Float16)0.f;
    _Float16 h2rh = (_Float16)h2r, h2ih = (_Float16)h2i;
    _Float16 bsrh = (_Float16)bsr, bsih = (_Float16)bsi;
    hf2 Ur, Ui, Qr, Qi;
    { hf2 t0 = {h2rh, HZ}, t1 = {HZ, h2rh}; Ur = jpar ? t1 : t0; }
    { hf2 t0 = {h2ih, HZ}, t1 = {HZ, h2ih}; Ui = jpar ? t1 : t0; }
    { hf2 t0 = {bsrh, HZ}, t1 = {HZ, bsrh}; Qr = l5 ? t1 : t0; }
    { hf2 t0 = {bsih, HZ}, t1 = {HZ, bsih}; Qi = l5 ? t1 : t0; }

    // ---- A-side cascade: wires 0..5 on (u0,u1); constants from lane 12+w ----
    stage<5>(12, lane, pk0,pk1,pk2,pk3,pk4,pk5,pk6,pk7, Ur, Ui);
    stage<4>(13, lane, pk0,pk1,pk2,pk3,pk4,pk5,pk6,pk7, Ur, Ui);
    stage<3>(14, lane, pk0,pk1,pk2,pk3,pk4,pk5,pk6,pk7, Ur, Ui);
    stage<2>(15, lane, pk0,pk1,pk2,pk3,pk4,pk5,pk6,pk7, Ur, Ui);
    stage<1>(16, lane, pk0,pk1,pk2,pk3,pk4,pk5,pk6,pk7, Ur, Ui);
    stage<0>(17, lane, pk0,pk1,pk2,pk3,pk4,pk5,pk6,pk7, Ur, Ui);
    // ---- B-side cascade: wires 6..11 on (q0,q1); constants from lane 18+m ----
    stage<5>(18, lane, pk0,pk1,pk2,pk3,pk4,pk5,pk6,pk7, Qr, Qi);
    stage<4>(19, lane, pk0,pk1,pk2,pk3,pk4,pk5,pk6,pk7, Qr, Qi);
    stage<3>(20, lane, pk0,pk1,pk2,pk3,pk4,pk5,pk6,pk7, Qr, Qi);
    stage<2>(21, lane, pk0,pk1,pk2,pk3,pk4,pk5,pk6,pk7, Qr, Qi);
    stage<1>(22, lane, pk0,pk1,pk2,pk3,pk4,pk5,pk6,pk7, Qr, Qi);
    stage<0>(23, lane, pk0,pk1,pk2,pk3,pk4,pk5,pk6,pk7, Qr, Qi);

    // ---- unpack to f32 ----
    float u0r = (float)Ur.x, u1r = (float)Ur.y;
    float u0i = (float)Ui.x, u1i = (float)Ui.y;
    float q0r = (float)Qr.x, q1r = (float)Qr.y;
    float q0i = (float)Qi.x, q1i = (float)Qi.y;

    // w_p = v6[p]*Q0 + v6[1-p]*Q1
    float w0r = (v6r0*q0r - v6i0*q0i) + (v6r1*q1r - v6i1*q1i);
    float w0i = (v6r0*q0i + v6i0*q0r) + (v6r1*q1i + v6i1*q1r);
    float w1r = (v6r1*q0r - v6i1*q0i) + (v6r0*q1r - v6i0*q1i);
    float w1i = (v6r1*q0i + v6i1*q0r) + (v6r0*q1i + v6i0*q1r);

    // Row/col quadratics
    float a0 = u0r*u0r + u0i*u0i;
    float a1 = u1r*u1r + u1i*u1i;
    float zr = u0r*u1r + u0i*u1i;
    float zi = u0i*u1r - u0r*u1i;
    float b0 = w0r*w0r + w0i*w0i;
    float b1 = w1r*w1r + w1i*w1i;
    float yr = w0r*w1r + w0i*w1i;
    float yi = w0i*w1r - w0r*w1i;

    // ---- phase 1: 8 uniform reductions via DPP (0 DS ops) ----
    const int par6 = __builtin_popcount((unsigned)lane) & 1;
    const float sgnf = par6 ? -1.f : 1.f;
    float Pb0 = rlane_f(wsum63(b0), 63);
    float Pb1 = rlane_f(wsum63(b1), 63);
    float Pyr = rlane_f(wsum63(yr), 63);
    float Pyi = rlane_f(wsum63(yi), 63);
    float Ta0 = rlane_f(wsum63(sgnf*a0), 63);
    float Ta1 = rlane_f(wsum63(sgnf*a1), 63);
    float Tzr = rlane_f(wsum63(sgnf*zr), 63);
    float Tzi = rlane_f(wsum63(sgnf*zi), 63);

    // ---- phase 2: per-lane bilinear combos (Ta*/Tz* uniform; no sgnf) ----
    float alpha = a0*Pb0 + a1*Pb1 + 2.f*(zr*Pyr - zi*Pyi);
    float beta  = Ta0*b0 + Ta1*b1 + 2.f*(Tzr*yr - Tzi*yi);

    // ---- phase 3: 12 signed output reductions via DPP ----
    const int m0 = ((lane>>5)&1) << 31;
    const int m1 = (__builtin_popcount((unsigned)(lane>>4)) & 1) << 31;
    const int m2 = (__builtin_popcount((unsigned)(lane>>3)) & 1) << 31;
    const int m3 = (__builtin_popcount((unsigned)(lane>>2)) & 1) << 31;
    const int m4 = (__builtin_popcount((unsigned)(lane>>1)) & 1) << 31;
    const int m5 = par6 << 31;
    float o0  = wsum63(xsign(alpha, m0));
    float o1  = wsum63(xsign(alpha, m1));
    float o2  = wsum63(xsign(alpha, m2));
    float o3  = wsum63(xsign(alpha, m3));
    float o4  = wsum63(xsign(alpha, m4));
    float o5  = wsum63(xsign(alpha, m5));
    float o6  = wsum63(xsign(beta,  m0));
    float o7  = wsum63(xsign(beta,  m1));
    float o8  = wsum63(xsign(beta,  m2));
    float o9  = wsum63(xsign(beta,  m3));
    float o10 = wsum63(xsign(beta,  m4));
    float o11 = wsum63(xsign(beta,  m5));

    if (lane == 63){
        float* o = out + (size_t)b * NQ;
        o[0] = o0;  o[1] = o1;  o[2]  = o2;  o[3]  = o3;
        o[4] = o4;  o[5] = o5;  o[6]  = o6;  o[7]  = o7;
        o[8] = o8;  o[9] = o9;  o[10] = o10; o[11] = o11;
    }
}

extern "C" void kernel_launch(void* const* d_in, const int* in_sizes, int n_in,
                              void* d_out, int out_size, void* d_ws, size_t ws_size,
                              hipStream_t stream){
    const float* x   = (const float*)d_in[0];
    const float* wts = (const float*)d_in[1];
    float* out = (float*)d_out;
    const int B = in_sizes[0] / NQ;

    qsim<<<(B + 3) / 4, 256, 0, stream>>>(x, wts, out, B);
}